// Round 7
// baseline (260.838 us; speedup 1.0000x reference)
//
#include <hip/hip_runtime.h>
#include <hip/hip_bf16.h>
#include <math.h>

// Problem constants
#define D_DIM 128
#define M_CODES 2048
#define BN_TOT 65536           // B*N = 16*4096
#define OUT_LOSS 8388608       // flat offset of loss
#define OUT_PERP 8388609       // flat offset of perp
#define OUT_IDX 8388610        // flat offset of indices
#define MARGIN 2e-3f           // covers ref fp32 noise (~1.6e-5) + bf16-split err

#define QB 64                  // queries per argmin block (2 q-waves share B via LDS)

// ws byte offsets
#define WS_L2K 0               // float l2k[2048]              (8 KB)
#define WS_PB 8192             // bf16 packed codebook, 1 MB: 64 pchunks x 16 KB
#define WS_IDX 1056768         // int best_idx[65536]          (256 KB)
#define WS_PART 1318912        // float loss_part[8192]        (32 KB)
#define WS_CNT 1351680         // int counts[2048]             (8 KB)
#define WS_FLAGCNT 1359872     // int flag_count               (pad to 1 KB)
#define WS_FLAGGED 1360896     // int flagged[65536]           (256 KB)

typedef __bf16 bf16x8 __attribute__((ext_vector_type(8)));
typedef float f32x4 __attribute__((ext_vector_type(4)));

// async 16B/lane global->LDS copy: LDS dest is wave-uniform base + lane*16
#define GLOAD_LDS16(g, l)                                         \
  __builtin_amdgcn_global_load_lds(                               \
      (const __attribute__((address_space(1))) void*)(g),         \
      (__attribute__((address_space(3))) void*)(l), 16, 0, 0)

#define MFMA16(a, b, c) __builtin_amdgcn_mfma_f32_16x16x32_bf16((a), (b), (c), 0, 0, 0)

// ---------------------------------------------------------------------------
// prep: fuses (a) emulated-np ||k||^2 (terms rounded fp32, fp64 sum, round
// back -> matches ref within ~1 ulp), (b) codebook prepack, (c) counts /
// flag_count zeroing. Grid 256x256.
//
// Pack layout (UNCHANGED, verified v3..v6): pchunk p (32 codes) occupies
// bytes [p*16384, (p+1)*16384). granule g = p*16 + cid (1 KB):
//   cid in [0,8):  hi part, ks = cid>>1, wc = cid&1
//   cid in [8,16): lo part, k2 = cid-8, ks = k2>>1, wc = k2&1
// lane l (col=l&15, quad=l>>4), elem j in [0,8):
//   value = w[p*32 + wc*16 + col][ks*32 + quad*8 + j]
// ---------------------------------------------------------------------------
__global__ __launch_bounds__(256) void prep_kernel(const float* __restrict__ w,
                                                   float* __restrict__ l2k,
                                                   __bf16* __restrict__ pb,
                                                   int* __restrict__ counts,
                                                   int* __restrict__ flagcnt) {
  int gid = blockIdx.x * 256 + threadIdx.x;

  if (gid < M_CODES) {
    const float4* p = (const float4*)(w + (size_t)gid * D_DIM);
    double s = 0.0;
#pragma unroll
    for (int j = 0; j < 32; ++j) {
      float4 v = p[j];
      s += (double)(v.x * v.x);
      s += (double)(v.y * v.y);
      s += (double)(v.z * v.z);
      s += (double)(v.w * v.w);
    }
    l2k[gid] = (float)s;
    counts[gid] = 0;
    if (gid == 0) *flagcnt = 0;
  }

  // pack: gid is a lane-granule id, 65536 total
  int lane = gid & 63;
  int g = gid >> 6;                          // granule 0..1023
  int cid = g & 15;
  int p = g >> 4;
  int k2 = cid & 7;
  int ks = k2 >> 1;
  int wc = k2 & 1;
  int code = p * 32 + wc * 16 + (lane & 15);
  int koff = ks * 32 + (lane >> 4) * 8;
  const float* src = w + (size_t)code * D_DIM + koff;
  float4 u = *(const float4*)src;
  float4 v = *(const float4*)(src + 4);
  float f[8] = {u.x, u.y, u.z, u.w, v.x, v.y, v.z, v.w};
  bf16x8 o;
#pragma unroll
  for (int j = 0; j < 8; ++j) {
    __bf16 hh = (__bf16)f[j];
    o[j] = (cid < 8) ? hh : (__bf16)(f[j] - (float)hh);
  }
  *(bf16x8*)(pb + (size_t)g * 512 + lane * 8) = o;
}

// max-form merge: (b,s)=best/second-best of acc (=sim-0.5*l2k; argmax),
// first-index tie-break
__device__ __forceinline__ void merge_bs(float& b, float& s, int& i,
                                         float ob, float os, int oi) {
  if (ob > b) {
    s = fmaxf(b, os);
    b = ob;
    i = oi;
  } else if (ob < b) {
    s = fmaxf(s, ob);
  } else {           // tie: gap 0 -> flagged -> fixup resolves exactly
    s = b;
    if (oi < i) i = oi;
  }
}

// 4-element fold slice (argmax, branchless second-max, pchunk-id index)
__device__ __forceinline__ void fold4(const f32x4& f, float (&m1r)[4],
                                      float (&m2r)[4], int (&bpr)[4], int pid) {
#pragma unroll
  for (int r = 0; r < 4; ++r) {
    float dd = f[r];
    bool gt = dd > m1r[r];
    m2r[r] = fmaxf(m2r[r], fminf(m1r[r], dd));
    bpr[r] = gt ? pid : bpr[r];
    m1r[r] = fmaxf(m1r[r], dd);
  }
}

// ---------------------------------------------------------------------------
// chunk_body: one 64-code chunk as FOUR m201-style phases (one per ks):
//   ph0: [stage pair 0][vmcnt(2) counted][barrier][ds_read frags ks0]
//        [lgkm(0)+sched_bar][acc init][setprio1][12 MFMA][setprio0]
//        [fold slice prev F00][barrier]
//   ph k=1..3: [ds_read frags ks=k][stage pair k][barrier][lgkm(0)+sched_bar]
//        [setprio1][12 MFMA][setprio0][fold slice][barrier]
// Counted vmcnt ONCE per chunk (never a full drain in steady state); the
// VMEM FIFO contains ONLY stage loads (l2k reads moved to LDS) so the count
// is exact: at ph0, outstanding = st(CH) leftovers + 2 just-issued st(CH+1)
// -> vmcnt(2) completes st(CH). Fold of chunk CH-1 (F regs) is spread one
// 4-elem slice per phase (nt0 in ph0/ph1, nt1 in ph2/ph3 -> ascending code
// order preserved for the first-index tie-break).
// ---------------------------------------------------------------------------
#define MFMA_KS(KS, H0, L0, H1, L1)                                   \
  A00 = MFMA16(al[0][KS], H0, A00); A10 = MFMA16(al[1][KS], H0, A10); \
  A01 = MFMA16(al[0][KS], H1, A01); A11 = MFMA16(al[1][KS], H1, A11); \
  A00 = MFMA16(ah[0][KS], L0, A00); A10 = MFMA16(ah[1][KS], L0, A10); \
  A01 = MFMA16(ah[0][KS], L1, A01); A11 = MFMA16(ah[1][KS], L1, A11); \
  A00 = MFMA16(ah[0][KS], H0, A00); A10 = MFMA16(ah[1][KS], H0, A10); \
  A01 = MFMA16(ah[0][KS], H1, A01); A11 = MFMA16(ah[1][KS], H1, A11);

template <int DOFOLD, int DOSTAGE>
__device__ __forceinline__ void chunk_body(
    int CH, int PREV, unsigned char* ldsBp, const char* pbase, int ldsw, int wv,
    const bf16x8 (&ah)[2][4], const bf16x8 (&al)[2][4],
    f32x4& A00, f32x4& A10, f32x4& A01, f32x4& A11,
    const f32x4& F00, const f32x4& F10, const f32x4& F01, const f32x4& F11,
    float ia, float ib,
    float (&m1)[2][4], float (&m2)[2][4], int (&bp)[2][4]) {
  const unsigned char* rb = ldsBp + (CH & 1) * 32768 + ldsw;
  unsigned char* db = ldsBp + ((CH & 1) ^ 1) * 32768 + wv * 8192;
  const char* sg = pbase + (size_t)(CH + 1) * 32768;

  // ---------------- phase 0 (ks=0) ----------------
  if (DOSTAGE) {
    GLOAD_LDS16(sg, db);
    GLOAD_LDS16(sg + 1024, db + 1024);
    asm volatile("s_waitcnt vmcnt(2)" ::: "memory");   // st(CH) complete
  } else {
    asm volatile("s_waitcnt vmcnt(0)" ::: "memory");   // last chunk
  }
  __builtin_amdgcn_s_barrier();                        // buf[CH] published
  {
    bf16x8 h0 = *(const bf16x8*)(rb);
    bf16x8 l0 = *(const bf16x8*)(rb + 8192);
    bf16x8 h1 = *(const bf16x8*)(rb + 16384);
    bf16x8 l1 = *(const bf16x8*)(rb + 24576);
    asm volatile("s_waitcnt lgkmcnt(0)" ::: "memory");
    __builtin_amdgcn_sched_barrier(0);
    A00 = (f32x4){ia, ia, ia, ia};
    A10 = (f32x4){ia, ia, ia, ia};
    A01 = (f32x4){ib, ib, ib, ib};
    A11 = (f32x4){ib, ib, ib, ib};
    __builtin_amdgcn_s_setprio(1);
    MFMA_KS(0, h0, l0, h1, l1)
    __builtin_amdgcn_s_setprio(0);
  }
  if (DOFOLD) fold4(F00, m1[0], m2[0], bp[0], PREV * 2 + 0);
  __builtin_amdgcn_s_barrier();

  // ---------------- phases 1..3 ----------------
#pragma unroll
  for (int k = 1; k < 4; ++k) {
    bf16x8 h0 = *(const bf16x8*)(rb + k * 2048);
    bf16x8 l0 = *(const bf16x8*)(rb + 8192 + k * 2048);
    bf16x8 h1 = *(const bf16x8*)(rb + 16384 + k * 2048);
    bf16x8 l1 = *(const bf16x8*)(rb + 24576 + k * 2048);
    if (DOSTAGE) {
      GLOAD_LDS16(sg + (2 * k) * 1024, db + (2 * k) * 1024);
      GLOAD_LDS16(sg + (2 * k + 1) * 1024, db + (2 * k + 1) * 1024);
    }
    __builtin_amdgcn_s_barrier();
    asm volatile("s_waitcnt lgkmcnt(0)" ::: "memory");
    __builtin_amdgcn_sched_barrier(0);
    __builtin_amdgcn_s_setprio(1);
    if (k == 1) { MFMA_KS(1, h0, l0, h1, l1) }
    else if (k == 2) { MFMA_KS(2, h0, l0, h1, l1) }
    else { MFMA_KS(3, h0, l0, h1, l1) }
    __builtin_amdgcn_s_setprio(0);
    if (DOFOLD) {
      if (k == 1) fold4(F10, m1[1], m2[1], bp[1], PREV * 2 + 0);
      else if (k == 2) fold4(F01, m1[0], m2[0], bp[0], PREV * 2 + 1);
      else fold4(F11, m1[1], m2[1], bp[1], PREV * 2 + 1);
    }
    __builtin_amdgcn_s_barrier();
  }
}

// ---------------------------------------------------------------------------
// MFMA argmin v7. Falsified so far: occupancy (2 vs 3 blk/CU), convoy/burst
// (24 vs 48 MFMA), bank conflicts (0), LDS read latency (v6 prefetch: null),
// naive counted-vmcnt graft (v4: regressed). All shared one structure:
// monolithic {stage, compute, fold, full-drain barrier} per chunk, MfmaUtil
// pinned 37-38%. v7 ports the m201 8-phase template (the HW-proven schedule
// that reaches 62% MfmaUtil at the same 2 waves/SIMD): per-ks phases with
// pre-barrier ds_read/stage issue, lgkm(0)+sched_barrier fences, setprio
// around MFMA clusters, counted vmcnt(2) once per chunk (VMEM FIFO = stage
// loads only: l2k lives in LDS, pre-scaled by -0.5), and T15-style deferred
// fold (chunk c folded in slices during chunk c+1; two named acc sets).
// MFMA order per accumulator unchanged -> bit-identical numerics; fold
// processes candidates in ascending code order -> tie-break preserved.
// ---------------------------------------------------------------------------
__global__ __launch_bounds__(256, 2) void argmin_mfma(
    const float* __restrict__ x, const __bf16* __restrict__ pb,
    const float* __restrict__ l2k, int* __restrict__ best_idx,
    int* __restrict__ flag_count, int* __restrict__ flagged) {
  __shared__ __align__(16) unsigned char ldsB[2 * 32768];
  __shared__ float l2s[2048];          // -0.5 * l2k (exact: *0.5 and negate)
  __shared__ float redB[4][32];
  __shared__ float redS[4][32];
  __shared__ int redI[4][32];

  const int tid = threadIdx.x;
  const int wv = tid >> 6;        // wave 0..3
  const int lane = tid & 63;
  const int col = lane & 15;      // MFMA n-index / A m-index
  const int quad = lane >> 4;     // 0..3
  const int wc = wv & 1;          // code-slice within pchunk
  const int wq = wv >> 1;         // query half (32 q each)
  const int q0 = blockIdx.x * QB;

  // ---- A fragments for this wave's 32 queries, fp32 -> hi/lo bf16, in regs
  bf16x8 ah[2][4], al[2][4];
#pragma unroll
  for (int mt = 0; mt < 2; ++mt) {
#pragma unroll
    for (int ks = 0; ks < 4; ++ks) {
      const float* xr =
          x + (size_t)(q0 + wq * 32 + 16 * mt + col) * D_DIM + 32 * ks + 8 * quad;
      float4 u = *(const float4*)xr;
      float4 v = *(const float4*)(xr + 4);
      float f[8] = {u.x, u.y, u.z, u.w, v.x, v.y, v.z, v.w};
      bf16x8 h, l;
#pragma unroll
      for (int j = 0; j < 8; ++j) {
        __bf16 hh = (__bf16)f[j];
        h[j] = hh;
        l[j] = (__bf16)(f[j] - (float)hh);
      }
      ah[mt][ks] = h;
      al[mt][ks] = l;
    }
  }

  // ---- l2s = -0.5 * l2k into LDS (exact scale; removes l2k from VMEM FIFO)
  {
    float4 a = ((const float4*)l2k)[2 * tid];
    float4 b = ((const float4*)l2k)[2 * tid + 1];
    float4 na = {-0.5f * a.x, -0.5f * a.y, -0.5f * a.z, -0.5f * a.w};
    float4 nb = {-0.5f * b.x, -0.5f * b.y, -0.5f * b.z, -0.5f * b.w};
    ((float4*)l2s)[2 * tid] = na;
    ((float4*)l2s)[2 * tid + 1] = nb;
  }

  // per-lane running argmax state over acc = sim - 0.5*l2k
  float m1[2][4], m2[2][4];
  int bp[2][4];                   // best pchunk id (full index rebuilt later)
#pragma unroll
  for (int mt = 0; mt < 2; ++mt)
#pragma unroll
    for (int r = 0; r < 4; ++r) {
      m1[mt][r] = -3.4e38f;
      m2[mt][r] = -3.4e38f;
      bp[mt][r] = 0;
    }

  const int ldsw = wc * 1024 + lane * 16;
  const int wcol = wc * 16 + col;
  const char* pbase = (const char*)pb + wv * 8192 + lane * 16;

  // ---- prologue: stage chunk 0, full drain once
  {
    unsigned char* d0 = ldsB + wv * 8192;
#pragma unroll
    for (int i = 0; i < 8; ++i) GLOAD_LDS16(pbase + i * 1024, d0 + i * 1024);
  }
  __syncthreads();                // st(0) + l2s + A-frag loads all complete

  f32x4 pA00 = {0, 0, 0, 0}, pA10 = {0, 0, 0, 0}, pA01 = {0, 0, 0, 0}, pA11 = {0, 0, 0, 0};
  f32x4 pB00 = {0, 0, 0, 0}, pB10 = {0, 0, 0, 0}, pB01 = {0, 0, 0, 0}, pB11 = {0, 0, 0, 0};

  float ia = l2s[wcol];           // chunk 0, nt0 (pre-scaled -0.5*l2k)
  float ib = l2s[wcol + 32];      // chunk 0, nt1

  // chunk 0 -> pA, no fold
  chunk_body<0, 1>(0, 0, ldsB, pbase, ldsw, wv, ah, al,
                   pA00, pA10, pA01, pA11, pB00, pB10, pB01, pB11,
                   ia, ib, m1, m2, bp);
  ia = l2s[64 + wcol];
  ib = l2s[96 + wcol];

#pragma unroll 1
  for (int ch = 1; ch <= 29; ch += 2) {
    // odd chunk -> pB, fold pA (chunk ch-1)
    chunk_body<1, 1>(ch, ch - 1, ldsB, pbase, ldsw, wv, ah, al,
                     pB00, pB10, pB01, pB11, pA00, pA10, pA01, pA11,
                     ia, ib, m1, m2, bp);
    {
      int b0 = (ch + 1) * 64 + wcol;
      ia = l2s[b0];
      ib = l2s[b0 + 32];
    }
    // even chunk -> pA, fold pB (chunk ch)
    chunk_body<1, 1>(ch + 1, ch, ldsB, pbase, ldsw, wv, ah, al,
                     pA00, pA10, pA01, pA11, pB00, pB10, pB01, pB11,
                     ia, ib, m1, m2, bp);
    {
      int b0 = (ch + 2) * 64 + wcol;
      ia = l2s[b0];
      ib = l2s[b0 + 32];
    }
  }

  // chunk 31 -> pB, fold pA (chunk 30); no stage (vmcnt(0) drains st(31))
  chunk_body<1, 0>(31, 30, ldsB, pbase, ldsw, wv, ah, al,
                   pB00, pB10, pB01, pB11, pA00, pA10, pA01, pA11,
                   ia, ib, m1, m2, bp);

  // final fold of chunk 31 (nt0 then nt1 -> ascending order preserved)
  fold4(pB00, m1[0], m2[0], bp[0], 62);
  fold4(pB10, m1[1], m2[1], bp[1], 62);
  fold4(pB01, m1[0], m2[0], bp[0], 63);
  fold4(pB11, m1[1], m2[1], bp[1], 63);

  // ---- Cross-lane reduction: 16 cols per quad-row ----
#pragma unroll
  for (int mt = 0; mt < 2; ++mt) {
#pragma unroll
    for (int r = 0; r < 4; ++r) {
      float b = m1[mt][r], s = m2[mt][r];
      int i = bp[mt][r] * 32 + wc * 16 + col;   // full code index
#pragma unroll
      for (int m = 1; m < 16; m <<= 1) {
        float ob = __shfl_xor(b, m);
        float os = __shfl_xor(s, m);
        int oi = __shfl_xor(i, m);
        merge_bs(b, s, i, ob, os, oi);
      }
      if (col == 0) {
        int qloc = 16 * mt + 4 * quad + r;
        redB[wv][qloc] = b;
        redS[wv][qloc] = s;
        redI[wv][qloc] = i;
      }
    }
  }
  __syncthreads();

  // ---- Final merge across the 2 code-slice waves of each query half ----
  if (tid < QB) {
    int wq2 = tid >> 5;           // which query half
    int ql = tid & 31;
    float b = -3.4e38f, s = -3.4e38f;
    int i = 0x7fffffff;
    merge_bs(b, s, i, redB[wq2 * 2 + 0][ql], redS[wq2 * 2 + 0][ql], redI[wq2 * 2 + 0][ql]);
    merge_bs(b, s, i, redB[wq2 * 2 + 1][ql], redS[wq2 * 2 + 1][ql], redI[wq2 * 2 + 1][ql]);
    best_idx[q0 + tid] = i;
    // dist gap = 2*(b - s) on acc scale
    if (2.0f * (b - s) < MARGIN) {
      int pos = atomicAdd(flag_count, 1);
      flagged[pos] = q0 + tid;
    }
  }
}

// ---------------------------------------------------------------------------
// Fixup: for flagged queries, emulate the reference's fp32 computation:
//   dist = fl32( fl32(l2q32 + l2k32[c]) - fl32(2 * fl32(q.k)) )
// q.k exact in fp64 then rounded once to fp32. First-index tie-break.
// ---------------------------------------------------------------------------
__global__ __launch_bounds__(256) void fixup_kernel(const float* __restrict__ x,
                                                    const float* __restrict__ w,
                                                    const float* __restrict__ l2k32,
                                                    const int* __restrict__ flagged,
                                                    const int* __restrict__ flag_count,
                                                    int* __restrict__ best_idx) {
  __shared__ float qs[D_DIM];
  __shared__ float l2q_sh;
  __shared__ float redD[256];
  __shared__ int redI[256];
  const int tid = threadIdx.x;
  const int n = *flag_count;
  for (int f = blockIdx.x; f < n; f += gridDim.x) {
    __syncthreads();
    int q = flagged[f];
    if (tid < D_DIM) qs[tid] = x[(size_t)q * D_DIM + tid];
    __syncthreads();
    if (tid == 0) {
      double s = 0.0;
      for (int d = 0; d < D_DIM; ++d) {
        float t = qs[d] * qs[d];
        s += (double)t;
      }
      l2q_sh = (float)s;
    }
    __syncthreads();
    const float l2q = l2q_sh;
    float bd = 3.4e38f;
    int bi = 0x7fffffff;
    for (int c = tid; c < M_CODES; c += 256) {
      const float4* wr = (const float4*)(w + (size_t)c * D_DIM);
      double s = 0.0;
#pragma unroll
      for (int j = 0; j < 32; ++j) {
        float4 v = wr[j];
        s = fma((double)qs[j * 4 + 0], (double)v.x, s);
        s = fma((double)qs[j * 4 + 1], (double)v.y, s);
        s = fma((double)qs[j * 4 + 2], (double)v.z, s);
        s = fma((double)qs[j * 4 + 3], (double)v.w, s);
      }
      float simf = (float)s;
      float S = l2q + l2k32[c];
      float T = 2.0f * simf;
      float dist = S - T;
      if (dist < bd) { bd = dist; bi = c; }
    }
    redD[tid] = bd;
    redI[tid] = bi;
    __syncthreads();
    for (int off = 128; off; off >>= 1) {
      if (tid < off) {
        float od = redD[tid + off];
        int oi = redI[tid + off];
        if (od < redD[tid] || (od == redD[tid] && oi < redI[tid])) {
          redD[tid] = od;
          redI[tid] = oi;
        }
      }
      __syncthreads();
    }
    if (tid == 0) best_idx[q] = redI[0];
  }
}

// ---------------------------------------------------------------------------
// Gather + straight-through output + loss partials + histogram + indices out
// ---------------------------------------------------------------------------
__global__ __launch_bounds__(256) void epilogue_kernel(const float* __restrict__ x,
                                                       const float* __restrict__ w,
                                                       const int* __restrict__ best_idx,
                                                       float* __restrict__ out,
                                                       float* __restrict__ part,
                                                       int* __restrict__ counts) {
  int gid = blockIdx.x * 256 + threadIdx.x;  // float4 id, 2,097,152 total
  int q = gid >> 5;
  int d4 = gid & 31;
  int idx = best_idx[q];
  float4 xv = ((const float4*)x)[gid];
  float4 wv = ((const float4*)w)[(size_t)idx * 32 + d4];
  float4 o;
  float t0 = wv.x - xv.x; o.x = xv.x + t0; float e0 = o.x - xv.x;
  float t1 = wv.y - xv.y; o.y = xv.y + t1; float e1 = o.y - xv.y;
  float t2 = wv.z - xv.z; o.z = xv.z + t2; float e2 = o.z - xv.z;
  float t3 = wv.w - xv.w; o.w = xv.w + t3; float e3 = o.w - xv.w;
  float ls = e0 * e0 + e1 * e1 + e2 * e2 + e3 * e3;
  ((float4*)out)[gid] = o;

  for (int off = 32; off; off >>= 1) ls += __shfl_down(ls, off);
  __shared__ float red[4];
  if ((threadIdx.x & 63) == 0) red[threadIdx.x >> 6] = ls;
  __syncthreads();
  if (threadIdx.x == 0) part[blockIdx.x] = red[0] + red[1] + red[2] + red[3];

  if (d4 == 0) {
    out[OUT_IDX + q] = (float)idx;
    atomicAdd(&counts[idx], 1);
  }
}

// ---------------------------------------------------------------------------
// Finalize: loss mean + perplexity
// ---------------------------------------------------------------------------
__global__ __launch_bounds__(256) void finalize_kernel(const int* __restrict__ counts,
                                                       const float* __restrict__ part,
                                                       float* __restrict__ out) {
  int tid = threadIdx.x;
  float ls = 0.f;
  for (int i = tid; i < 8192; i += 256) ls += part[i];
  float es = 0.f;
  for (int i = tid; i < M_CODES; i += 256) {
    float p = (float)counts[i] * (1.0f / 65536.0f);
    es += p * logf(p + 1e-10f);
  }
  for (int off = 32; off; off >>= 1) {
    ls += __shfl_down(ls, off);
    es += __shfl_down(es, off);
  }
  __shared__ float redl[4], rede[4];
  if ((tid & 63) == 0) {
    redl[tid >> 6] = ls;
    rede[tid >> 6] = es;
  }
  __syncthreads();
  if (tid == 0) {
    out[OUT_LOSS] = (redl[0] + redl[1] + redl[2] + redl[3]) * (1.0f / 8388608.0f);
    out[OUT_PERP] = expf(-(rede[0] + rede[1] + rede[2] + rede[3]));
  }
}

extern "C" void kernel_launch(void* const* d_in, const int* in_sizes, int n_in,
                              void* d_out, int out_size, void* d_ws, size_t ws_size,
                              hipStream_t stream) {
  const float* x = (const float*)d_in[0];
  const float* w = (const float*)d_in[1];
  float* out = (float*)d_out;
  char* ws = (char*)d_ws;
  float* l2k = (float*)(ws + WS_L2K);
  __bf16* pb = (__bf16*)(ws + WS_PB);
  int* bidx = (int*)(ws + WS_IDX);
  float* part = (float*)(ws + WS_PART);
  int* counts = (int*)(ws + WS_CNT);
  int* flagcnt = (int*)(ws + WS_FLAGCNT);
  int* flagged = (int*)(ws + WS_FLAGGED);

  prep_kernel<<<256, 256, 0, stream>>>(w, l2k, pb, counts, flagcnt);
  argmin_mfma<<<BN_TOT / QB, 256, 0, stream>>>(x, pb, l2k, bidx, flagcnt, flagged);
  fixup_kernel<<<256, 256, 0, stream>>>(x, w, l2k, flagged, flagcnt, bidx);
  epilogue_kernel<<<8192, 256, 0, stream>>>(x, w, bidx, out, part, counts);
  finalize_kernel<<<1, 256, 0, stream>>>(counts, part, out);
}

// Round 8
// 237.231 us; speedup vs baseline: 1.0995x; 1.0995x over previous
//
#include <hip/hip_runtime.h>
#include <hip/hip_bf16.h>
#include <math.h>

// Problem constants
#define D_DIM 128
#define M_CODES 2048
#define BN_TOT 65536           // B*N = 16*4096
#define OUT_LOSS 8388608       // flat offset of loss
#define OUT_PERP 8388609       // flat offset of perp
#define OUT_IDX 8388610        // flat offset of indices
#define MARGIN 2e-3f           // covers ref fp32 noise (~1.6e-5) + bf16-split err

#define QB 128                 // queries per argmin block (4 q-groups x 2 slices)

// ws byte offsets
#define WS_L2K 0               // float l2k[2048]              (8 KB)
#define WS_PB 8192             // bf16 packed codebook, 1 MB: 64 pchunks x 16 KB
#define WS_IDX 1056768         // int best_idx[65536]          (256 KB)
#define WS_PART 1318912        // float loss_part[8192]        (32 KB)
#define WS_CNT 1351680         // int counts[2048]             (8 KB)
#define WS_FLAGCNT 1359872     // int flag_count               (pad to 1 KB)
#define WS_FLAGGED 1360896     // int flagged[65536]           (256 KB)

typedef __bf16 bf16x8 __attribute__((ext_vector_type(8)));
typedef float f32x4 __attribute__((ext_vector_type(4)));

// async 16B/lane global->LDS copy: LDS dest is wave-uniform base + lane*16
#define GLOAD_LDS16(g, l)                                         \
  __builtin_amdgcn_global_load_lds(                               \
      (const __attribute__((address_space(1))) void*)(g),         \
      (__attribute__((address_space(3))) void*)(l), 16, 0, 0)

#define MFMA16(a, b, c) __builtin_amdgcn_mfma_f32_16x16x32_bf16((a), (b), (c), 0, 0, 0)

// ---------------------------------------------------------------------------
// prep: fuses (a) emulated-np ||k||^2 (terms rounded fp32, fp64 sum, round
// back -> matches ref within ~1 ulp), (b) codebook prepack, (c) counts /
// flag_count zeroing. Grid 256x256.
//
// Pack layout (UNCHANGED, verified v3..v6): pchunk p (32 codes) occupies
// bytes [p*16384, (p+1)*16384). granule g = p*16 + cid (1 KB):
//   cid in [0,8):  hi part, ks = cid>>1, wc = cid&1
//   cid in [8,16): lo part, k2 = cid-8, ks = k2>>1, wc = k2&1
// lane l (col=l&15, quad=l>>4), elem j in [0,8):
//   value = w[p*32 + wc*16 + col][ks*32 + quad*8 + j]
// ---------------------------------------------------------------------------
__global__ __launch_bounds__(256) void prep_kernel(const float* __restrict__ w,
                                                   float* __restrict__ l2k,
                                                   __bf16* __restrict__ pb,
                                                   int* __restrict__ counts,
                                                   int* __restrict__ flagcnt) {
  int gid = blockIdx.x * 256 + threadIdx.x;

  if (gid < M_CODES) {
    const float4* p = (const float4*)(w + (size_t)gid * D_DIM);
    double s = 0.0;
#pragma unroll
    for (int j = 0; j < 32; ++j) {
      float4 v = p[j];
      s += (double)(v.x * v.x);
      s += (double)(v.y * v.y);
      s += (double)(v.z * v.z);
      s += (double)(v.w * v.w);
    }
    l2k[gid] = (float)s;
    counts[gid] = 0;
    if (gid == 0) *flagcnt = 0;
  }

  // pack: gid is a lane-granule id, 65536 total
  int lane = gid & 63;
  int g = gid >> 6;                          // granule 0..1023
  int cid = g & 15;
  int p = g >> 4;
  int k2 = cid & 7;
  int ks = k2 >> 1;
  int wc = k2 & 1;
  int code = p * 32 + wc * 16 + (lane & 15);
  int koff = ks * 32 + (lane >> 4) * 8;
  const float* src = w + (size_t)code * D_DIM + koff;
  float4 u = *(const float4*)src;
  float4 v = *(const float4*)(src + 4);
  float f[8] = {u.x, u.y, u.z, u.w, v.x, v.y, v.z, v.w};
  bf16x8 o;
#pragma unroll
  for (int j = 0; j < 8; ++j) {
    __bf16 hh = (__bf16)f[j];
    o[j] = (cid < 8) ? hh : (__bf16)(f[j] - (float)hh);
  }
  *(bf16x8*)(pb + (size_t)g * 512 + lane * 8) = o;
}

// max-form merge: (b,s)=best/second-best of acc (=sim-0.5*l2k; argmax),
// first-index tie-break
__device__ __forceinline__ void merge_bs(float& b, float& s, int& i,
                                         float ob, float os, int oi) {
  if (ob > b) {
    s = fmaxf(b, os);
    b = ob;
    i = oi;
  } else if (ob < b) {
    s = fmaxf(s, ob);
  } else {           // tie: gap 0 -> flagged -> fixup resolves exactly
    s = b;
    if (oi < i) i = oi;
  }
}

// ---------------------------------------------------------------------------
// MFMA argmin v8. Model from 7 rounds of counters: time = rounds x per-block
// serial chain; chain/chunk-step ~= 3100cy FIXED (barrier skew + drain) +
// ~470cy per 32 codes. v6.1 = 2 rounds x 32 steps x ~4440cy = 118us (exact).
// Schedule edits (v4 counted-vmcnt, v6 reg-prefetch, v7 phase template) all
// failed to shrink the fixed cost. v8 shrinks ROUNDS instead: QB=128, 8-wave
// 512-thread blocks (4 q-groups x 2 code-slices) -> grid 512 = 2 blocks/CU
// resident in ONE round. Per-wave work & chunk structure byte-identical to
// verified v6.1; only macro-geometry changes. Codebook L2 traffic halves.
// VGPR 88 fits the 128 cap at 4 waves/SIMD (launch_bounds(512,4));
// LDS 68.6KB -> 2 blocks/CU.
// ---------------------------------------------------------------------------
__global__ __launch_bounds__(512, 4) void argmin_mfma(
    const float* __restrict__ x, const __bf16* __restrict__ pb,
    const float* __restrict__ l2k, int* __restrict__ best_idx,
    int* __restrict__ flag_count, int* __restrict__ flagged) {
  __shared__ __align__(16) unsigned char ldsB[2 * 32768];
  __shared__ float redB[8][32];
  __shared__ float redS[8][32];
  __shared__ int redI[8][32];

  const int tid = threadIdx.x;
  const int wv = tid >> 6;        // wave 0..7
  const int lane = tid & 63;
  const int col = lane & 15;      // MFMA n-index / A m-index
  const int quad = lane >> 4;     // 0..3
  const int wc = wv & 1;          // code-slice within pchunk
  const int wq = wv >> 1;         // query group 0..3 (32 q each)
  const int q0 = blockIdx.x * QB;

  // ---- A fragments for this wave's 32 queries, fp32 -> hi/lo bf16, in regs
  bf16x8 ah[2][4], al[2][4];
#pragma unroll
  for (int mt = 0; mt < 2; ++mt) {
#pragma unroll
    for (int ks = 0; ks < 4; ++ks) {
      const float* xr =
          x + (size_t)(q0 + wq * 32 + 16 * mt + col) * D_DIM + 32 * ks + 8 * quad;
      float4 u = *(const float4*)xr;
      float4 v = *(const float4*)(xr + 4);
      float f[8] = {u.x, u.y, u.z, u.w, v.x, v.y, v.z, v.w};
      bf16x8 h, l;
#pragma unroll
      for (int j = 0; j < 8; ++j) {
        __bf16 hh = (__bf16)f[j];
        h[j] = hh;
        l[j] = (__bf16)(f[j] - (float)hh);
      }
      ah[mt][ks] = h;
      al[mt][ks] = l;
    }
  }

  // per-lane running argmax state over acc = sim - 0.5*l2k
  float m1[2][4], m2[2][4];
  int bp[2][4];                   // best pchunk id (full index rebuilt later)
#pragma unroll
  for (int mt = 0; mt < 2; ++mt)
#pragma unroll
    for (int r = 0; r < 4; ++r) {
      m1[mt][r] = -3.4e38f;
      m2[mt][r] = -3.4e38f;
      bp[mt][r] = 0;
    }

  const int ldsw = wc * 1024 + lane * 16;
  const float* l2p = l2k + wc * 16 + col;

  // stage chunk ch (64 codes = 32 KB = pchunks 2ch, 2ch+1); 4 granules/wave.
  // db MUST include the per-wave dest offset (+wv*4096) — v6 lesson.
  auto stage = [&](int ch, unsigned char* db) {
    const char* s = (const char*)pb + (size_t)ch * 32768 + wv * 4096 + lane * 16;
#pragma unroll
    for (int i = 0; i < 4; ++i) GLOAD_LDS16(s + i * 1024, db + i * 1024);
  };

  stage(0, ldsB + wv * 4096);     // per-wave dest offset!
  float l2a = l2p[0];
  float l2b = l2p[32];
  __syncthreads();   // drains vmcnt -> stage(0) complete

#pragma unroll 1
  for (int ch = 0; ch < 32; ++ch) {
    const int buf = ch & 1;
    if (ch < 31) stage(ch + 1, ldsB + (buf ^ 1) * 32768 + wv * 4096);
    float l2na = 0.f, l2nb = 0.f;
    if (ch < 31) {                          // l2 for chunk ch+1 (latency hidden)
      l2na = l2p[(2 * ch + 2) * 32];
      l2nb = l2p[(2 * ch + 3) * 32];
    }

    // ---- compute chunk ch: 48 MFMA, explicit 1-ks-ahead B prefetch ----
    const unsigned char* rb = ldsB + buf * 32768 + ldsw;
    float ia = -0.5f * l2a, ib = -0.5f * l2b;
    f32x4 a00 = (f32x4){ia, ia, ia, ia};
    f32x4 a10 = (f32x4){ia, ia, ia, ia};
    f32x4 a01 = (f32x4){ib, ib, ib, ib};
    f32x4 a11 = (f32x4){ib, ib, ib, ib};

    bf16x8 h0 = *(const bf16x8*)(rb);              // ks cur, nt0 hi
    bf16x8 l0 = *(const bf16x8*)(rb + 8192);       // ks cur, nt0 lo
    bf16x8 h1 = *(const bf16x8*)(rb + 16384);      // ks cur, nt1 hi
    bf16x8 l1 = *(const bf16x8*)(rb + 24576);      // ks cur, nt1 lo

#define DO_KS(KS, PRE)                                                    \
    {                                                                     \
      bf16x8 nh0, nl0, nh1, nl1;                                          \
      if (PRE) {                                                          \
        nh0 = *(const bf16x8*)(rb + ((KS) + 1) * 2048);                   \
        nl0 = *(const bf16x8*)(rb + 8192 + ((KS) + 1) * 2048);            \
        nh1 = *(const bf16x8*)(rb + 16384 + ((KS) + 1) * 2048);           \
        nl1 = *(const bf16x8*)(rb + 24576 + ((KS) + 1) * 2048);           \
      }                                                                   \
      a00 = MFMA16(al[0][KS], h0, a00);                                   \
      a10 = MFMA16(al[1][KS], h0, a10);                                   \
      a01 = MFMA16(al[0][KS], h1, a01);                                   \
      a11 = MFMA16(al[1][KS], h1, a11);                                   \
      a00 = MFMA16(ah[0][KS], l0, a00);                                   \
      a10 = MFMA16(ah[1][KS], l0, a10);                                   \
      a01 = MFMA16(ah[0][KS], l1, a01);                                   \
      a11 = MFMA16(ah[1][KS], l1, a11);                                   \
      a00 = MFMA16(ah[0][KS], h0, a00);                                   \
      a10 = MFMA16(ah[1][KS], h0, a10);                                   \
      a01 = MFMA16(ah[0][KS], h1, a01);                                   \
      a11 = MFMA16(ah[1][KS], h1, a11);                                   \
      if (PRE) { h0 = nh0; l0 = nl0; h1 = nh1; l1 = nl1; }                \
    }
    DO_KS(0, 1)
    DO_KS(1, 1)
    DO_KS(2, 1)
    DO_KS(3, 0)
#undef DO_KS

    // fold (argmax, branchless second-max, pchunk-id index).
    // candidates ascend over (ch, nt) -> strict > keeps first index.
    // nt0 = {a00,a10}, nt1 = {a01,a11}; iteration order matches v5/v6.1.
#pragma unroll
    for (int mt = 0; mt < 2; ++mt) {
#pragma unroll
      for (int r = 0; r < 4; ++r) {
        float dd = (mt == 0) ? a00[r] : a10[r];
        bool gt = dd > m1[mt][r];
        m2[mt][r] = fmaxf(m2[mt][r], fminf(m1[mt][r], dd));
        bp[mt][r] = gt ? (ch * 2 + 0) : bp[mt][r];
        m1[mt][r] = fmaxf(m1[mt][r], dd);
      }
    }
#pragma unroll
    for (int mt = 0; mt < 2; ++mt) {
#pragma unroll
      for (int r = 0; r < 4; ++r) {
        float dd = (mt == 0) ? a01[r] : a11[r];
        bool gt = dd > m1[mt][r];
        m2[mt][r] = fmaxf(m2[mt][r], fminf(m1[mt][r], dd));
        bp[mt][r] = gt ? (ch * 2 + 1) : bp[mt][r];
        m1[mt][r] = fmaxf(m1[mt][r], dd);
      }
    }

    l2a = l2na;
    l2b = l2nb;
    __syncthreads();              // next buf staged + this buf reads done
  }

  // ---- Cross-lane reduction: 16 cols per quad-row ----
#pragma unroll
  for (int mt = 0; mt < 2; ++mt) {
#pragma unroll
    for (int r = 0; r < 4; ++r) {
      float b = m1[mt][r], s = m2[mt][r];
      int i = bp[mt][r] * 32 + wc * 16 + col;   // full code index
#pragma unroll
      for (int m = 1; m < 16; m <<= 1) {
        float ob = __shfl_xor(b, m);
        float os = __shfl_xor(s, m);
        int oi = __shfl_xor(i, m);
        merge_bs(b, s, i, ob, os, oi);
      }
      if (col == 0) {
        int qloc = 16 * mt + 4 * quad + r;
        redB[wv][qloc] = b;
        redS[wv][qloc] = s;
        redI[wv][qloc] = i;
      }
    }
  }
  __syncthreads();

  // ---- Final merge across the 2 code-slice waves of each query group ----
  if (tid < QB) {
    int wg = tid >> 5;            // query group 0..3
    int ql = tid & 31;
    float b = -3.4e38f, s = -3.4e38f;
    int i = 0x7fffffff;
    merge_bs(b, s, i, redB[wg * 2 + 0][ql], redS[wg * 2 + 0][ql], redI[wg * 2 + 0][ql]);
    merge_bs(b, s, i, redB[wg * 2 + 1][ql], redS[wg * 2 + 1][ql], redI[wg * 2 + 1][ql]);
    best_idx[q0 + tid] = i;
    // dist gap = 2*(b - s) on acc scale
    if (2.0f * (b - s) < MARGIN) {
      int pos = atomicAdd(flag_count, 1);
      flagged[pos] = q0 + tid;
    }
  }
}

// ---------------------------------------------------------------------------
// Fixup: for flagged queries, emulate the reference's fp32 computation:
//   dist = fl32( fl32(l2q32 + l2k32[c]) - fl32(2 * fl32(q.k)) )
// q.k exact in fp64 then rounded once to fp32. First-index tie-break.
// ---------------------------------------------------------------------------
__global__ __launch_bounds__(256) void fixup_kernel(const float* __restrict__ x,
                                                    const float* __restrict__ w,
                                                    const float* __restrict__ l2k32,
                                                    const int* __restrict__ flagged,
                                                    const int* __restrict__ flag_count,
                                                    int* __restrict__ best_idx) {
  __shared__ float qs[D_DIM];
  __shared__ float l2q_sh;
  __shared__ float redD[256];
  __shared__ int redI[256];
  const int tid = threadIdx.x;
  const int n = *flag_count;
  for (int f = blockIdx.x; f < n; f += gridDim.x) {
    __syncthreads();
    int q = flagged[f];
    if (tid < D_DIM) qs[tid] = x[(size_t)q * D_DIM + tid];
    __syncthreads();
    if (tid == 0) {
      double s = 0.0;
      for (int d = 0; d < D_DIM; ++d) {
        float t = qs[d] * qs[d];
        s += (double)t;
      }
      l2q_sh = (float)s;
    }
    __syncthreads();
    const float l2q = l2q_sh;
    float bd = 3.4e38f;
    int bi = 0x7fffffff;
    for (int c = tid; c < M_CODES; c += 256) {
      const float4* wr = (const float4*)(w + (size_t)c * D_DIM);
      double s = 0.0;
#pragma unroll
      for (int j = 0; j < 32; ++j) {
        float4 v = wr[j];
        s = fma((double)qs[j * 4 + 0], (double)v.x, s);
        s = fma((double)qs[j * 4 + 1], (double)v.y, s);
        s = fma((double)qs[j * 4 + 2], (double)v.z, s);
        s = fma((double)qs[j * 4 + 3], (double)v.w, s);
      }
      float simf = (float)s;
      float S = l2q + l2k32[c];
      float T = 2.0f * simf;
      float dist = S - T;
      if (dist < bd) { bd = dist; bi = c; }
    }
    redD[tid] = bd;
    redI[tid] = bi;
    __syncthreads();
    for (int off = 128; off; off >>= 1) {
      if (tid < off) {
        float od = redD[tid + off];
        int oi = redI[tid + off];
        if (od < redD[tid] || (od == redD[tid] && oi < redI[tid])) {
          redD[tid] = od;
          redI[tid] = oi;
        }
      }
      __syncthreads();
    }
    if (tid == 0) best_idx[q] = redI[0];
  }
}

// ---------------------------------------------------------------------------
// Gather + straight-through output + loss partials + histogram + indices out
// ---------------------------------------------------------------------------
__global__ __launch_bounds__(256) void epilogue_kernel(const float* __restrict__ x,
                                                       const float* __restrict__ w,
                                                       const int* __restrict__ best_idx,
                                                       float* __restrict__ out,
                                                       float* __restrict__ part,
                                                       int* __restrict__ counts) {
  int gid = blockIdx.x * 256 + threadIdx.x;  // float4 id, 2,097,152 total
  int q = gid >> 5;
  int d4 = gid & 31;
  int idx = best_idx[q];
  float4 xv = ((const float4*)x)[gid];
  float4 wv = ((const float4*)w)[(size_t)idx * 32 + d4];
  float4 o;
  float t0 = wv.x - xv.x; o.x = xv.x + t0; float e0 = o.x - xv.x;
  float t1 = wv.y - xv.y; o.y = xv.y + t1; float e1 = o.y - xv.y;
  float t2 = wv.z - xv.z; o.z = xv.z + t2; float e2 = o.z - xv.z;
  float t3 = wv.w - xv.w; o.w = xv.w + t3; float e3 = o.w - xv.w;
  float ls = e0 * e0 + e1 * e1 + e2 * e2 + e3 * e3;
  ((float4*)out)[gid] = o;

  for (int off = 32; off; off >>= 1) ls += __shfl_down(ls, off);
  __shared__ float red[4];
  if ((threadIdx.x & 63) == 0) red[threadIdx.x >> 6] = ls;
  __syncthreads();
  if (threadIdx.x == 0) part[blockIdx.x] = red[0] + red[1] + red[2] + red[3];

  if (d4 == 0) {
    out[OUT_IDX + q] = (float)idx;
    atomicAdd(&counts[idx], 1);
  }
}

// ---------------------------------------------------------------------------
// Finalize: loss mean + perplexity
// ---------------------------------------------------------------------------
__global__ __launch_bounds__(256) void finalize_kernel(const int* __restrict__ counts,
                                                       const float* __restrict__ part,
                                                       float* __restrict__ out) {
  int tid = threadIdx.x;
  float ls = 0.f;
  for (int i = tid; i < 8192; i += 256) ls += part[i];
  float es = 0.f;
  for (int i = tid; i < M_CODES; i += 256) {
    float p = (float)counts[i] * (1.0f / 65536.0f);
    es += p * logf(p + 1e-10f);
  }
  for (int off = 32; off; off >>= 1) {
    ls += __shfl_down(ls, off);
    es += __shfl_down(es, off);
  }
  __shared__ float redl[4], rede[4];
  if ((tid & 63) == 0) {
    redl[tid >> 6] = ls;
    rede[tid >> 6] = es;
  }
  __syncthreads();
  if (tid == 0) {
    out[OUT_LOSS] = (redl[0] + redl[1] + redl[2] + redl[3]) * (1.0f / 8388608.0f);
    out[OUT_PERP] = expf(-(rede[0] + rede[1] + rede[2] + rede[3]));
  }
}

extern "C" void kernel_launch(void* const* d_in, const int* in_sizes, int n_in,
                              void* d_out, int out_size, void* d_ws, size_t ws_size,
                              hipStream_t stream) {
  const float* x = (const float*)d_in[0];
  const float* w = (const float*)d_in[1];
  float* out = (float*)d_out;
  char* ws = (char*)d_ws;
  float* l2k = (float*)(ws + WS_L2K);
  __bf16* pb = (__bf16*)(ws + WS_PB);
  int* bidx = (int*)(ws + WS_IDX);
  float* part = (float*)(ws + WS_PART);
  int* counts = (int*)(ws + WS_CNT);
  int* flagcnt = (int*)(ws + WS_FLAGCNT);
  int* flagged = (int*)(ws + WS_FLAGGED);

  prep_kernel<<<256, 256, 0, stream>>>(w, l2k, pb, counts, flagcnt);
  argmin_mfma<<<BN_TOT / QB, 512, 0, stream>>>(x, pb, l2k, bidx, flagcnt, flagged);
  fixup_kernel<<<256, 256, 0, stream>>>(x, w, l2k, flagged, flagcnt, bidx);
  epilogue_kernel<<<8192, 256, 0, stream>>>(x, w, bidx, out, part, counts);
  finalize_kernel<<<1, 256, 0, stream>>>(counts, part, out);
}